// Round 15
// baseline (179.372 us; speedup 1.0000x reference)
//
#include <hip/hip_runtime.h>

#define HID 1024
#define HEADS 16
#define HD 64
#define TAB 129
#define QSTR 136
#define BATCH 8
#define SEQ 512

typedef unsigned int uint;
typedef unsigned short ushort;
typedef unsigned char uchar;
typedef __attribute__((ext_vector_type(4))) float f32x4;
typedef __attribute__((ext_vector_type(8))) __bf16 bf16x8;

__device__ __forceinline__ ushort f2b(float x) {
    uint b = __float_as_uint(x);
    uint r = (b + 0x7fffu + ((b >> 16) & 1u)) >> 16;
    return (ushort)r;
}
__device__ __forceinline__ uint pk(float lo, float hi) {
    return (uint)f2b(lo) | ((uint)f2b(hi) << 16);
}
__device__ __forceinline__ float b2f(ushort u) {
    return __uint_as_float(((uint)u) << 16);
}
union U16x8 { uint u[4]; bf16x8 v; ushort s[8]; uint4 q; };
__device__ __forceinline__ bf16x8 pack8(float a0, float a1, float a2, float a3,
                                        float a4, float a5, float a6, float a7) {
    U16x8 r;
    r.u[0] = pk(a0, a1); r.u[1] = pk(a2, a3);
    r.u[2] = pk(a4, a5); r.u[3] = pk(a6, a7);
    return r.v;
}

#define GL16(gp, lp) __builtin_amdgcn_global_load_lds( \
    (const __attribute__((address_space(1))) void*)(gp), \
    (__attribute__((address_space(3))) void*)(lp), 16, 0, 0)

#define LDS_BARRIER() do { \
        asm volatile("s_waitcnt lgkmcnt(0)" ::: "memory"); \
        __builtin_amdgcn_s_barrier(); \
    } while (0)

// ---------------------------------------------------------------------------
// convert fp32 -> bf16 (unchanged)
// ---------------------------------------------------------------------------
struct ConvArgs { const float* src[7]; ushort* dst[7]; };

__global__ __launch_bounds__(256) void convert_bf16(ConvArgs ca) {
    int bid = blockIdx.x;
    int ti, lb;
    if (bid < 6144) { ti = bid >> 11; lb = bid & 2047; }
    else { int r = bid - 6144; ti = 3 + (r >> 9); lb = r & 511; }
    const float* s = ca.src[ti] + (size_t)lb * 2048 + (threadIdx.x << 3);
    ushort*      d = ca.dst[ti] + (size_t)lb * 2048 + (threadIdx.x << 3);
    float4 a = *(const float4*)s;
    float4 c = *(const float4*)(s + 4);
    uint4 u;
    u.x = pk(a.x, a.y); u.y = pk(a.z, a.w);
    u.z = pk(c.x, c.y); u.w = pk(c.z, c.w);
    *(uint4*)d = u;
}

// ---------------------------------------------------------------------------
// QKV GEMM: 128x128 tile, z-batched, flattened XCD-bijective grid (768 blk).
// ---------------------------------------------------------------------------
struct GemmArgs {
    const ushort* A[3];
    const ushort* W[3];
    const float*  bias[3];
    ushort*       Cb[3];
};

__global__ __launch_bounds__(256) void gemm_qkv(GemmArgs ga) {
    const int N = HID, K = HID;
    __shared__ ushort As[2][128 * 32];
    __shared__ ushort Bs[2][128 * 32];
    const int tid = threadIdx.x;
    const int bid = blockIdx.x;
    const int swz = (bid & 7) * 96 + (bid >> 3);   // 768 blocks, 96/XCD
    const int z   = swz >> 8;                      // 0..2
    const int rem = swz & 255;                     // 32 m x 8 n
    const int m0  = (rem >> 3) * 128;
    const int n0  = (rem & 7) * 128;
    const ushort* A = ga.A[z];
    const ushort* W = ga.W[z];

    const int w  = tid >> 6;
    const int l  = tid & 63;
    const int lr = l & 15;
    const int lg = l >> 4;
    const int wm = w >> 1;
    const int wn = w & 1;

    const int sr = tid >> 2;
    const int sc = tid & 3;
    const int g  = sc ^ ((sr >> 1) & 3);
    const ushort* Ag0 = A + (size_t)(m0 + sr)      * K + g * 8;
    const ushort* Ag1 = A + (size_t)(m0 + sr + 64) * K + g * 8;
    const ushort* Wg0 = W + (size_t)(n0 + sr)      * K + g * 8;
    const ushort* Wg1 = W + (size_t)(n0 + sr + 64) * K + g * 8;

    f32x4 acc[4][4];
#pragma unroll
    for (int mt = 0; mt < 4; ++mt)
#pragma unroll
        for (int nt = 0; nt < 4; ++nt) acc[mt][nt] = (f32x4){0.f, 0.f, 0.f, 0.f};

#define STAGE(buf, k0) do { \
        GL16(Ag0 + (k0), &As[buf][w * 512]); \
        GL16(Ag1 + (k0), &As[buf][2048 + w * 512]); \
        GL16(Wg0 + (k0), &Bs[buf][w * 512]); \
        GL16(Wg1 + (k0), &Bs[buf][2048 + w * 512]); \
    } while (0)

    const int swl = (lr >> 1) & 3;
#define COMPUTE(buf) do { \
        bf16x8 af[4], bf[4]; \
        _Pragma("unroll") \
        for (int mt = 0; mt < 4; ++mt) \
            af[mt] = *(const bf16x8*)&As[buf][(wm * 64 + mt * 16 + lr) * 32 + (lg ^ swl) * 8]; \
        _Pragma("unroll") \
        for (int nt = 0; nt < 4; ++nt) \
            bf[nt] = *(const bf16x8*)&Bs[buf][(wn * 64 + nt * 16 + lr) * 32 + (lg ^ swl) * 8]; \
        _Pragma("unroll") \
        for (int mt = 0; mt < 4; ++mt) \
            _Pragma("unroll") \
            for (int nt = 0; nt < 4; ++nt) \
                acc[mt][nt] = __builtin_amdgcn_mfma_f32_16x16x32_bf16(af[mt], bf[nt], acc[mt][nt], 0, 0, 0); \
    } while (0)

    STAGE(0, 0);
    __syncthreads();
    const int nk = K / 32;
    for (int t = 0; t < nk - 1; ++t) {
        STAGE((t + 1) & 1, (size_t)(t + 1) * 32);
        COMPUTE(t & 1);
        __syncthreads();
    }
    COMPUTE((nk - 1) & 1);

    const float* bias = ga.bias[z];
    float bv[4];
#pragma unroll
    for (int nt = 0; nt < 4; ++nt) bv[nt] = bias[n0 + wn * 64 + nt * 16 + lr];
    ushort* Cb = ga.Cb[z];
#pragma unroll
    for (int mt = 0; mt < 4; ++mt)
#pragma unroll
        for (int r4 = 0; r4 < 4; ++r4) {
            size_t m = m0 + wm * 64 + mt * 16 + lg * 4 + r4;
            ushort* crow = Cb + m * N + n0 + wn * 64 + lr;
#pragma unroll
            for (int nt = 0; nt < 4; ++nt)
                crow[nt * 16] = f2b(acc[mt][nt][r4] + bv[nt]);
        }
#undef STAGE
#undef COMPUTE
}

// ---------------------------------------------------------------------------
// Wo GEMM, BN=64 tile, flattened XCD-bijective grid (512 blk)
// ---------------------------------------------------------------------------
__global__ __launch_bounds__(256) void gemm_wo(const ushort* __restrict__ A,
                                               const ushort* __restrict__ W,
                                               const float* __restrict__ bias,
                                               float* __restrict__ Cf) {
    const int N = HID, K = HID;
    __shared__ ushort As[2][128 * 32];
    __shared__ ushort Bs[2][64 * 32];
    const int tid = threadIdx.x;
    const int bid = blockIdx.x;
    const int swz = (bid & 7) * 64 + (bid >> 3);   // 512 blocks, 64/XCD
    const int m0 = (swz >> 4) * 128;
    const int n0 = (swz & 15) * 64;

    const int w  = tid >> 6;
    const int l  = tid & 63;
    const int lr = l & 15;
    const int lg = l >> 4;
    const int wm = w >> 1;
    const int wn = w & 1;

    const int sr = tid >> 2;
    const int sc = tid & 3;
    const int g  = sc ^ ((sr >> 1) & 3);
    const ushort* Ag0 = A + (size_t)(m0 + sr)      * K + g * 8;
    const ushort* Ag1 = A + (size_t)(m0 + sr + 64) * K + g * 8;
    const ushort* Wg0 = W + (size_t)(n0 + sr)      * K + g * 8;

    f32x4 acc[4][2];
#pragma unroll
    for (int mt = 0; mt < 4; ++mt)
#pragma unroll
        for (int nt = 0; nt < 2; ++nt) acc[mt][nt] = (f32x4){0.f, 0.f, 0.f, 0.f};

#define STAGE(buf, k0) do { \
        GL16(Ag0 + (k0), &As[buf][w * 512]); \
        GL16(Ag1 + (k0), &As[buf][2048 + w * 512]); \
        GL16(Wg0 + (k0), &Bs[buf][w * 512]); \
    } while (0)

    const int swl = (lr >> 1) & 3;
#define COMPUTE(buf) do { \
        bf16x8 af[4], bf[2]; \
        _Pragma("unroll") \
        for (int mt = 0; mt < 4; ++mt) \
            af[mt] = *(const bf16x8*)&As[buf][(wm * 64 + mt * 16 + lr) * 32 + (lg ^ swl) * 8]; \
        _Pragma("unroll") \
        for (int nt = 0; nt < 2; ++nt) \
            bf[nt] = *(const bf16x8*)&Bs[buf][(wn * 32 + nt * 16 + lr) * 32 + (lg ^ swl) * 8]; \
        _Pragma("unroll") \
        for (int mt = 0; mt < 4; ++mt) \
            _Pragma("unroll") \
            for (int nt = 0; nt < 2; ++nt) \
                acc[mt][nt] = __builtin_amdgcn_mfma_f32_16x16x32_bf16(af[mt], bf[nt], acc[mt][nt], 0, 0, 0); \
    } while (0)

    STAGE(0, 0);
    __syncthreads();
    const int nk = K / 32;
    for (int t = 0; t < nk - 1; ++t) {
        STAGE((t + 1) & 1, (size_t)(t + 1) * 32);
        COMPUTE(t & 1);
        __syncthreads();
    }
    COMPUTE((nk - 1) & 1);

    float bv[2];
#pragma unroll
    for (int nt = 0; nt < 2; ++nt) bv[nt] = bias[n0 + wn * 32 + nt * 16 + lr];
#pragma unroll
    for (int mt = 0; mt < 4; ++mt)
#pragma unroll
        for (int r4 = 0; r4 < 4; ++r4) {
            size_t m = m0 + wm * 64 + mt * 16 + lg * 4 + r4;
            float* crow = Cf + m * N + n0 + wn * 32 + lr;
#pragma unroll
            for (int nt = 0; nt < 2; ++nt)
                crow[nt * 16] = acc[mt][nt][r4] + bv[nt];
        }
#undef STAGE
#undef COMPUTE
}

// ---------------------------------------------------------------------------
// prep_kernel: qtab (MFMA) + V-transpose + tvT2 (padded [64][160]) + fm->u8
// ---------------------------------------------------------------------------
__global__ __launch_bounds__(256) void prep_kernel(const ushort* __restrict__ qb,
                                                   const float* __restrict__ table_k,
                                                   const ushort* __restrict__ vb,
                                                   const float* __restrict__ table_v,
                                                   const int* __restrict__ fmat,
                                                   ushort* __restrict__ qtab,
                                                   ushort* __restrict__ vT,
                                                   ushort* __restrict__ tvT2,
                                                   uchar* __restrict__ fm8) {
    __shared__ __align__(16) ushort shmem[144 * 72];
    const int wg  = blockIdx.x;
    const int tid = threadIdx.x;

    if (wg < 256) {
        const int h    = wg & 15;
        const int half = (wg >> 4) & 1;
        const int b    = wg >> 5;
        const int q0   = half * 256;
        ushort* tk = shmem;
        for (int i = tid; i < TAB * 8; i += 256) {
            int row = i >> 3, gr = i & 7;
            const float* src = table_k + row * HD + gr * 8;
            float4 a = *(const float4*)src;
            float4 c = *(const float4*)(src + 4);
            uint4 u;
            u.x = pk(a.x, a.y); u.y = pk(a.z, a.w);
            u.z = pk(c.x, c.y); u.w = pk(c.z, c.w);
            *(uint4*)&tk[row * 72 + gr * 8] = u;
        }
        __syncthreads();

        const int w  = tid >> 6;
        const int l  = tid & 63;
        const int lr = l & 15;
        const int lg = l >> 4;
        bf16x8 qf[4][2];
#pragma unroll
        for (int qt = 0; qt < 4; ++qt) {
            const ushort* qrow = qb + ((size_t)(b * SEQ) + q0 + w * 64 + qt * 16 + lr) * HID + h * HD;
            qf[qt][0] = *(const bf16x8*)(qrow + lg * 8);
            qf[qt][1] = *(const bf16x8*)(qrow + 32 + lg * 8);
        }
        ushort* outbase = qtab + ((size_t)(b * HEADS + h) * SEQ + q0 + w * 64) * QSTR;
#pragma unroll
        for (int mt = 0; mt < 9; ++mt) {
            bf16x8 tf0 = *(const bf16x8*)&tk[(mt * 16 + lr) * 72 + lg * 8];
            bf16x8 tf1 = *(const bf16x8*)&tk[(mt * 16 + lr) * 72 + 32 + lg * 8];
#pragma unroll
            for (int qt = 0; qt < 4; ++qt) {
                f32x4 acc = (f32x4){0.f, 0.f, 0.f, 0.f};
                acc = __builtin_amdgcn_mfma_f32_16x16x32_bf16(tf0, qf[qt][0], acc, 0, 0, 0);
                acc = __builtin_amdgcn_mfma_f32_16x16x32_bf16(tf1, qf[qt][1], acc, 0, 0, 0);
                ushort* orow = outbase + (size_t)(qt * 16 + lr) * QSTR;
                if (mt < 8) {
                    uint2 pu;
                    pu.x = pk(acc[0], acc[1]); pu.y = pk(acc[2], acc[3]);
                    *(uint2*)&orow[mt * 16 + lg * 4] = pu;
                } else if (lg == 0) {
                    orow[128] = f2b(acc[0]);
                }
            }
        }
    } else if (wg < 768) {
        const int vw = wg - 256;
        ushort* tile = shmem;
        const int b = vw >> 6, h = (vw >> 2) & 15, kc = vw & 3;
        const int k0 = kc * 128;
        {
            const int kr = tid >> 1, dc = (tid & 1) * 32;
            const ushort* src = vb + ((size_t)(b * SEQ) + k0 + kr) * HID + h * 64 + dc;
#pragma unroll
            for (int j = 0; j < 4; ++j) {
                uint4 u = *(const uint4*)(src + j * 8);
                *(uint4*)&tile[kr * 72 + dc + j * 8] = u;
            }
        }
        __syncthreads();
        {
            const int dr = tid >> 2, kc2 = (tid & 3) * 32;
            ushort* dst = vT + ((size_t)(b * 16 + h) * 64 + dr) * 512 + k0 + kc2;
#pragma unroll
            for (int j = 0; j < 4; ++j) {
                U16x8 o;
#pragma unroll
                for (int i = 0; i < 8; ++i)
                    o.s[i] = tile[(kc2 + j * 8 + i) * 72 + dr];
                *(uint4*)(dst + j * 8) = o.q;
            }
        }
    } else if (wg == 768) {
        for (int i = tid; i < 64 * 160; i += 256) {
            int d = i / 160;
            int c = i - d * 160;
            tvT2[i] = (c < TAB) ? f2b(table_v[(size_t)c * HD + d]) : (ushort)0;
        }
    } else {
        const size_t base = (size_t)(wg - 769) * 2048 + (size_t)tid * 8;
        int4 a = *(const int4*)(fmat + base);
        int4 c = *(const int4*)(fmat + base + 4);
        uint lo = (uint)a.x | ((uint)a.y << 8) | ((uint)a.z << 16) | ((uint)a.w << 24);
        uint hi = (uint)c.x | ((uint)c.y << 8) | ((uint)c.z << 16) | ((uint)c.w << 24);
        uint2 o; o.x = lo; o.y = hi;
        *(uint2*)(fm8 + base) = o;
    }
}

// ---------------------------------------------------------------------------
// qk_gemm: S[bh, q, k] = Q . K^T  (bf16 out, unchanged R13)
// ---------------------------------------------------------------------------
__global__ __launch_bounds__(256) void qk_gemm(const ushort* __restrict__ qb,
                                               const ushort* __restrict__ kb,
                                               ushort* __restrict__ S) {
    __shared__ ushort As[2][128 * 32];
    __shared__ ushort Bs[2][128 * 32];
    const int tid = threadIdx.x;
    const int m0 = blockIdx.x * 128;
    const int n0 = blockIdx.y * 128;
    const int bh = blockIdx.z;
    const int b = bh >> 4, h = bh & 15;
    const size_t rowQ = (size_t)b * SEQ;

    const int w  = tid >> 6;
    const int l  = tid & 63;
    const int lr = l & 15;
    const int lg = l >> 4;
    const int wm = w >> 1;
    const int wn = w & 1;

    const int sr = tid >> 2;
    const int sc = tid & 3;
    const int g  = sc ^ ((sr >> 1) & 3);
    const ushort* Ag0 = qb + (rowQ + m0 + sr)      * HID + h * HD + g * 8;
    const ushort* Ag1 = qb + (rowQ + m0 + sr + 64) * HID + h * HD + g * 8;
    const ushort* Wg0 = kb + (rowQ + n0 + sr)      * HID + h * HD + g * 8;
    const ushort* Wg1 = kb + (rowQ + n0 + sr + 64) * HID + h * HD + g * 8;

    GL16(Ag0,      &As[0][w * 512]); GL16(Ag1,      &As[0][2048 + w * 512]);
    GL16(Wg0,      &Bs[0][w * 512]); GL16(Wg1,      &Bs[0][2048 + w * 512]);
    GL16(Ag0 + 32, &As[1][w * 512]); GL16(Ag1 + 32, &As[1][2048 + w * 512]);
    GL16(Wg0 + 32, &Bs[1][w * 512]); GL16(Wg1 + 32, &Bs[1][2048 + w * 512]);

    f32x4 acc[4][4];
#pragma unroll
    for (int mt = 0; mt < 4; ++mt)
#pragma unroll
        for (int nt = 0; nt < 4; ++nt) acc[mt][nt] = (f32x4){0.f, 0.f, 0.f, 0.f};

    const int swl = (lr >> 1) & 3;
    __syncthreads();
#pragma unroll
    for (int buf = 0; buf < 2; ++buf) {
        bf16x8 af[4], bf[4];
#pragma unroll
        for (int mt = 0; mt < 4; ++mt)
            af[mt] = *(const bf16x8*)&As[buf][(wm * 64 + mt * 16 + lr) * 32 + (lg ^ swl) * 8];
#pragma unroll
        for (int nt = 0; nt < 4; ++nt)
            bf[nt] = *(const bf16x8*)&Bs[buf][(wn * 64 + nt * 16 + lr) * 32 + (lg ^ swl) * 8];
#pragma unroll
        for (int mt = 0; mt < 4; ++mt)
#pragma unroll
            for (int nt = 0; nt < 4; ++nt)
                acc[mt][nt] = __builtin_amdgcn_mfma_f32_16x16x32_bf16(af[mt], bf[nt], acc[mt][nt], 0, 0, 0);
    }

    ushort* Sb = S + (size_t)bh * SEQ * SEQ;
#pragma unroll
    for (int mt = 0; mt < 4; ++mt)
#pragma unroll
        for (int r4 = 0; r4 < 4; ++r4) {
            int m = m0 + wm * 64 + mt * 16 + lg * 4 + r4;
            ushort* srow = Sb + (size_t)m * SEQ + n0 + wn * 64 + lr;
#pragma unroll
            for (int nt = 0; nt < 4; ++nt)
                srow[nt * 16] = f2b(acc[mt][nt][r4]);
        }
}

// ---------------------------------------------------------------------------
// smpv_kernel (fused sm+pv): block = (64 q-rows, bh), 256 thr, 4 waves.
// Wave w owns rows [w*16, w*16+16): reads raw S frags from global, exp's
// in-register (A-frag rows are lane-local!), accumulates unnormalized
// O = P~.V^T via MFMA, bins via wave-private u32 ds_add, then w2 = bins.tvT2
// and a single normalization at the end. ONE barrier (prologue only).
// ---------------------------------------------------------------------------
__global__ __launch_bounds__(256) void smpv_kernel(const ushort* __restrict__ S,
                                                   const uchar* __restrict__ fm8,
                                                   const ushort* __restrict__ qt,
                                                   const ushort* __restrict__ vT,
                                                   const ushort* __restrict__ tvT2,
                                                   ushort* __restrict__ x) {
    constexpr float FIX = 65536.0f;
    constexpr float INV_FIX = 1.0f / 65536.0f;
    __shared__ __align__(16) uint   bins[64 * 132];    // 33,792 B
    __shared__ __align__(16) ushort qtb[64 * QSTR];    // 17,408 B
    __shared__ float rowsum[64];

    const int tid = threadIdx.x;
    const int w   = tid >> 6;
    const int l   = tid & 63;
    const int lr  = l & 15;
    const int lg  = l >> 4;

    // XCD swizzle: 1024 blocks, 128/XCD -> 16 bh per XCD chunk
    const int bid = blockIdx.x;
    const int swz = (bid & 7) * 128 + (bid >> 3);
    const int bh  = swz >> 3;
    const int m0  = (swz & 7) * 64;
    const int b   = bh >> 4, h = bh & 15;

    // ---- prologue: stage qtab rows, zero bins ----
    {
        const uint4* src = (const uint4*)(qt + ((size_t)bh * SEQ + m0) * QSTR);
        uint4* dst = (uint4*)qtb;
        for (int i = tid; i < 64 * QSTR / 8; i += 256) dst[i] = src[i];
    }
    {
        uint4 z = {0u, 0u, 0u, 0u};
        uint4* dz = (uint4*)bins;
        for (int i = tid; i < 64 * 132 / 4; i += 256) dz[i] = z;
    }
    LDS_BARRIER();

    const int myrow = w * 16 + lr;                 // this lane's A-row
    const ushort* Srow  = S + ((size_t)bh * SEQ + m0 + myrow) * SEQ;
    const uchar*  fmrow = fm8 + ((size_t)(b * SEQ) + m0 + myrow) * SEQ;
    const ushort* qrow  = qtb + myrow * QSTR;
    uint*         brow  = bins + myrow * 132;
    const ushort* vbase = vT + (size_t)bh * 64 * 512;

    f32x4 acc[4];
#pragma unroll
    for (int nt = 0; nt < 4; ++nt) acc[nt] = (f32x4){0.f, 0.f, 0.f, 0.f};
    float lsum = 0.f;

    for (int ks = 0; ks < 16; ++ks) {
        const int k0 = ks * 32 + lg * 8;
        U16x8 sv;
        sv.q = *(const uint4*)(Srow + k0);
        uint2 fm = *(const uint2*)(fmrow + k0);
        int ts[8];
        ts[0] = fm.x & 255; ts[1] = (fm.x >> 8) & 255;
        ts[2] = (fm.x >> 16) & 255; ts[3] = fm.x >> 24;
        ts[4] = fm.y & 255; ts[5] = (fm.y >> 8) & 255;
        ts[6] = (fm.y >> 16) & 255; ts[7] = fm.y >> 24;
        float p[8];
#pragma unroll
        for (int j = 0; j < 8; ++j) {
            p[j] = __expf((b2f(sv.s[j]) + b2f(qrow[ts[j]])) * 0.125f);
            lsum += p[j];
        }
#pragma unroll
        for (int j = 0; j < 8; ++j)
            __hip_atomic_fetch_add(&brow[ts[j]], (uint)(p[j] * FIX),
                                   __ATOMIC_RELAXED, __HIP_MEMORY_SCOPE_WORKGROUP);
        bf16x8 af = pack8(p[0], p[1], p[2], p[3], p[4], p[5], p[6], p[7]);
#pragma unroll
        for (int nt = 0; nt < 4; ++nt) {
            bf16x8 bf_ = *(const bf16x8*)(vbase + (size_t)(nt * 16 + lr) * 512 + k0);
            acc[nt] = __builtin_amdgcn_mfma_f32_16x16x32_bf16(af, bf_, acc[nt], 0, 0, 0);
        }
    }
    // row sums (4 lanes lg=0..3 hold partials of row myrow)
    lsum += __shfl_xor(lsum, 16);
    lsum += __shfl_xor(lsum, 32);
    if (lg == 0) rowsum[myrow] = lsum;

    // wave-local DS ordering: bins adds + rowsum write visible to this wave
    asm volatile("s_waitcnt lgkmcnt(0)" ::: "memory");

    // ---- w2: O += bins~ . tvT2  (4 chunks of 32 t; unnormalized) ----
#pragma unroll
    for (int ks = 0; ks < 4; ++ks) {
        const int t0 = ks * 32 + lg * 8;
        const uint* bp = brow + t0;
        bf16x8 af = pack8((float)bp[0] * INV_FIX, (float)bp[1] * INV_FIX,
                          (float)bp[2] * INV_FIX, (float)bp[3] * INV_FIX,
                          (float)bp[4] * INV_FIX, (float)bp[5] * INV_FIX,
                          (float)bp[6] * INV_FIX, (float)bp[7] * INV_FIX);
#pragma unroll
        for (int nt = 0; nt < 4; ++nt) {
            bf16x8 bf_ = *(const bf16x8*)(tvT2 + (size_t)(nt * 16 + lr) * 160 + t0);
            acc[nt] = __builtin_amdgcn_mfma_f32_16x16x32_bf16(af, bf_, acc[nt], 0, 0, 0);
        }
    }

    // ---- epilogue: tail bin t=128, normalize, write x ----
    float iv[4], nb[4];
#pragma unroll
    for (int r = 0; r < 4; ++r) {
        const int crow = w * 16 + lg * 4 + r;       // own wave's rows
        iv[r] = 1.f / rowsum[crow];
        nb[r] = (float)bins[crow * 132 + 128] * INV_FIX;
    }
#pragma unroll
    for (int nt = 0; nt < 4; ++nt) {
        float tv = b2f(tvT2[(size_t)(nt * 16 + lr) * 160 + 128]);
#pragma unroll
        for (int r = 0; r < 4; ++r)
            acc[nt][r] = (acc[nt][r] + nb[r] * tv) * iv[r];
    }
    {
        ushort* orow = x + ((size_t)(b * SEQ) + m0 + w * 16 + lg * 4) * HID + h * HD;
#pragma unroll
        for (int r = 0; r < 4; ++r)
#pragma unroll
            for (int nt = 0; nt < 4; ++nt)
                orow[(size_t)r * HID + nt * 16 + lr] = f2b(acc[nt][r]);
    }
}

// ---------------------------------------------------------------------------
extern "C" void kernel_launch(void* const* d_in, const int* in_sizes, int n_in,
                              void* d_out, int out_size, void* d_ws, size_t ws_size,
                              hipStream_t stream) {
    const float* query = (const float*)d_in[0];
    const float* key   = (const float*)d_in[1];
    const float* value = (const float*)d_in[2];
    const int*   fmat  = (const int*)d_in[3];
    const float* Wq = (const float*)d_in[4];
    const float* bq = (const float*)d_in[5];
    const float* Wk = (const float*)d_in[6];
    const float* bk = (const float*)d_in[7];
    const float* Wv = (const float*)d_in[8];
    const float* bv = (const float*)d_in[9];
    const float* Wo = (const float*)d_in[10];
    const float* bo = (const float*)d_in[11];
    const float* table_k = (const float*)d_in[12];
    const float* table_v = (const float*)d_in[13];

    const size_t nBLD = (size_t)BATCH * SEQ * HID;
    const size_t nW   = (size_t)HID * HID;
    ushort* us = (ushort*)d_ws;
    ushort* qin16 = us;                 us += nBLD;   // reused as vT
    ushort* kin16 = us;                 us += nBLD;   // reused as tvT2
    ushort* vin16 = us;                 us += nBLD;
    ushort* wq16  = us;                 us += nW;
    ushort* wk16  = us;                 us += nW;
    ushort* wv16  = us;                 us += nW;
    ushort* wo16  = us;                 us += nW;
    ushort* qb16  = us;                 us += nBLD;
    ushort* kb16  = us;                 us += nBLD;
    ushort* vb16  = us;                 us += nBLD;
    ushort* qt16  = us;                 us += (size_t)BATCH * HEADS * SEQ * QSTR;
    ushort* xb16  = us;                 us += nBLD;
    uchar*  fm8   = (uchar*)us;         us += (size_t)BATCH * SEQ * SEQ / 2;
    ushort* Sbuf  = us;                 us += (size_t)BATCH * HEADS * SEQ * SEQ;

    ConvArgs ca;
    ca.src[0] = query; ca.src[1] = key; ca.src[2] = value;
    ca.src[3] = Wq; ca.src[4] = Wk; ca.src[5] = Wv; ca.src[6] = Wo;
    ca.dst[0] = qin16; ca.dst[1] = kin16; ca.dst[2] = vin16;
    ca.dst[3] = wq16; ca.dst[4] = wk16; ca.dst[5] = wv16; ca.dst[6] = wo16;
    convert_bf16<<<dim3(8192), 256, 0, stream>>>(ca);

    GemmArgs gq = {};
    gq.A[0] = qin16; gq.A[1] = kin16; gq.A[2] = vin16;
    gq.W[0] = wq16;  gq.W[1] = wk16;  gq.W[2] = wv16;
    gq.bias[0] = bq; gq.bias[1] = bk; gq.bias[2] = bv;
    gq.Cb[0] = qb16; gq.Cb[1] = kb16; gq.Cb[2] = vb16;
    gemm_qkv<<<dim3(768), 256, 0, stream>>>(gq);

    ushort* vTbuf  = qin16;
    ushort* tvTbuf = kin16;

    prep_kernel<<<dim3(1793), 256, 0, stream>>>(qb16, table_k, vb16, table_v,
                                                fmat, qt16, vTbuf, tvTbuf, fm8);

    qk_gemm<<<dim3(4, 4, 128), 256, 0, stream>>>(qb16, kb16, Sbuf);
    smpv_kernel<<<dim3(1024), 256, 0, stream>>>(Sbuf, fm8, qt16, vTbuf, tvTbuf, xb16);

    gemm_wo<<<dim3(512), 256, 0, stream>>>(xb16, wo16, bo, (float*)d_out);
}

// Round 16
// 167.674 us; speedup vs baseline: 1.0698x; 1.0698x over previous
//
#include <hip/hip_runtime.h>

#define HID 1024
#define HEADS 16
#define HD 64
#define TAB 129
#define QSTR 136
#define BATCH 8
#define SEQ 512

typedef unsigned int uint;
typedef unsigned short ushort;
typedef unsigned char uchar;
typedef __attribute__((ext_vector_type(4))) float f32x4;
typedef __attribute__((ext_vector_type(8))) __bf16 bf16x8;

__device__ __forceinline__ ushort f2b(float x) {
    uint b = __float_as_uint(x);
    uint r = (b + 0x7fffu + ((b >> 16) & 1u)) >> 16;
    return (ushort)r;
}
__device__ __forceinline__ uint pk(float lo, float hi) {
    return (uint)f2b(lo) | ((uint)f2b(hi) << 16);
}
__device__ __forceinline__ float b2f(ushort u) {
    return __uint_as_float(((uint)u) << 16);
}
union U16x8 { uint u[4]; bf16x8 v; ushort s[8]; uint4 q; };
__device__ __forceinline__ bf16x8 pack8(float a0, float a1, float a2, float a3,
                                        float a4, float a5, float a6, float a7) {
    U16x8 r;
    r.u[0] = pk(a0, a1); r.u[1] = pk(a2, a3);
    r.u[2] = pk(a4, a5); r.u[3] = pk(a6, a7);
    return r.v;
}

#define GL16(gp, lp) __builtin_amdgcn_global_load_lds( \
    (const __attribute__((address_space(1))) void*)(gp), \
    (__attribute__((address_space(3))) void*)(lp), 16, 0, 0)

#define LDS_BARRIER() do { \
        asm volatile("s_waitcnt lgkmcnt(0)" ::: "memory"); \
        __builtin_amdgcn_s_barrier(); \
    } while (0)

// ---------------------------------------------------------------------------
// convert fp32 -> bf16 (unchanged)
// ---------------------------------------------------------------------------
struct ConvArgs { const float* src[7]; ushort* dst[7]; };

__global__ __launch_bounds__(256) void convert_bf16(ConvArgs ca) {
    int bid = blockIdx.x;
    int ti, lb;
    if (bid < 6144) { ti = bid >> 11; lb = bid & 2047; }
    else { int r = bid - 6144; ti = 3 + (r >> 9); lb = r & 511; }
    const float* s = ca.src[ti] + (size_t)lb * 2048 + (threadIdx.x << 3);
    ushort*      d = ca.dst[ti] + (size_t)lb * 2048 + (threadIdx.x << 3);
    float4 a = *(const float4*)s;
    float4 c = *(const float4*)(s + 4);
    uint4 u;
    u.x = pk(a.x, a.y); u.y = pk(a.z, a.w);
    u.z = pk(c.x, c.y); u.w = pk(c.z, c.w);
    *(uint4*)d = u;
}

// ---------------------------------------------------------------------------
// QKV GEMM: 128x128 tile, z-batched, flattened XCD-bijective grid (768 blk).
// ---------------------------------------------------------------------------
struct GemmArgs {
    const ushort* A[3];
    const ushort* W[3];
    const float*  bias[3];
    ushort*       Cb[3];
};

__global__ __launch_bounds__(256) void gemm_qkv(GemmArgs ga) {
    const int N = HID, K = HID;
    __shared__ ushort As[2][128 * 32];
    __shared__ ushort Bs[2][128 * 32];
    const int tid = threadIdx.x;
    const int bid = blockIdx.x;
    const int swz = (bid & 7) * 96 + (bid >> 3);   // 768 blocks, 96/XCD
    const int z   = swz >> 8;
    const int rem = swz & 255;
    const int m0  = (rem >> 3) * 128;
    const int n0  = (rem & 7) * 128;
    const ushort* A = ga.A[z];
    const ushort* W = ga.W[z];

    const int w  = tid >> 6;
    const int l  = tid & 63;
    const int lr = l & 15;
    const int lg = l >> 4;
    const int wm = w >> 1;
    const int wn = w & 1;

    const int sr = tid >> 2;
    const int sc = tid & 3;
    const int g  = sc ^ ((sr >> 1) & 3);
    const ushort* Ag0 = A + (size_t)(m0 + sr)      * K + g * 8;
    const ushort* Ag1 = A + (size_t)(m0 + sr + 64) * K + g * 8;
    const ushort* Wg0 = W + (size_t)(n0 + sr)      * K + g * 8;
    const ushort* Wg1 = W + (size_t)(n0 + sr + 64) * K + g * 8;

    f32x4 acc[4][4];
#pragma unroll
    for (int mt = 0; mt < 4; ++mt)
#pragma unroll
        for (int nt = 0; nt < 4; ++nt) acc[mt][nt] = (f32x4){0.f, 0.f, 0.f, 0.f};

#define STAGE(buf, k0) do { \
        GL16(Ag0 + (k0), &As[buf][w * 512]); \
        GL16(Ag1 + (k0), &As[buf][2048 + w * 512]); \
        GL16(Wg0 + (k0), &Bs[buf][w * 512]); \
        GL16(Wg1 + (k0), &Bs[buf][2048 + w * 512]); \
    } while (0)

    const int swl = (lr >> 1) & 3;
#define COMPUTE(buf) do { \
        bf16x8 af[4], bf[4]; \
        _Pragma("unroll") \
        for (int mt = 0; mt < 4; ++mt) \
            af[mt] = *(const bf16x8*)&As[buf][(wm * 64 + mt * 16 + lr) * 32 + (lg ^ swl) * 8]; \
        _Pragma("unroll") \
        for (int nt = 0; nt < 4; ++nt) \
            bf[nt] = *(const bf16x8*)&Bs[buf][(wn * 64 + nt * 16 + lr) * 32 + (lg ^ swl) * 8]; \
        _Pragma("unroll") \
        for (int mt = 0; mt < 4; ++mt) \
            _Pragma("unroll") \
            for (int nt = 0; nt < 4; ++nt) \
                acc[mt][nt] = __builtin_amdgcn_mfma_f32_16x16x32_bf16(af[mt], bf[nt], acc[mt][nt], 0, 0, 0); \
    } while (0)

    STAGE(0, 0);
    __syncthreads();
    const int nk = K / 32;
    for (int t = 0; t < nk - 1; ++t) {
        STAGE((t + 1) & 1, (size_t)(t + 1) * 32);
        COMPUTE(t & 1);
        __syncthreads();
    }
    COMPUTE((nk - 1) & 1);

    const float* bias = ga.bias[z];
    float bv[4];
#pragma unroll
    for (int nt = 0; nt < 4; ++nt) bv[nt] = bias[n0 + wn * 64 + nt * 16 + lr];
    ushort* Cb = ga.Cb[z];
#pragma unroll
    for (int mt = 0; mt < 4; ++mt)
#pragma unroll
        for (int r4 = 0; r4 < 4; ++r4) {
            size_t m = m0 + wm * 64 + mt * 16 + lg * 4 + r4;
            ushort* crow = Cb + m * N + n0 + wn * 64 + lr;
#pragma unroll
            for (int nt = 0; nt < 4; ++nt)
                crow[nt * 16] = f2b(acc[mt][nt][r4] + bv[nt]);
        }
#undef STAGE
#undef COMPUTE
}

// ---------------------------------------------------------------------------
// Wo GEMM, BN=64 tile, flattened XCD-bijective grid (512 blk, unchanged)
// ---------------------------------------------------------------------------
__global__ __launch_bounds__(256) void gemm_wo(const ushort* __restrict__ A,
                                               const ushort* __restrict__ W,
                                               const float* __restrict__ bias,
                                               float* __restrict__ Cf) {
    const int N = HID, K = HID;
    __shared__ ushort As[2][128 * 32];
    __shared__ ushort Bs[2][64 * 32];
    const int tid = threadIdx.x;
    const int bid = blockIdx.x;
    const int swz = (bid & 7) * 64 + (bid >> 3);
    const int m0 = (swz >> 4) * 128;
    const int n0 = (swz & 15) * 64;

    const int w  = tid >> 6;
    const int l  = tid & 63;
    const int lr = l & 15;
    const int lg = l >> 4;
    const int wm = w >> 1;
    const int wn = w & 1;

    const int sr = tid >> 2;
    const int sc = tid & 3;
    const int g  = sc ^ ((sr >> 1) & 3);
    const ushort* Ag0 = A + (size_t)(m0 + sr)      * K + g * 8;
    const ushort* Ag1 = A + (size_t)(m0 + sr + 64) * K + g * 8;
    const ushort* Wg0 = W + (size_t)(n0 + sr)      * K + g * 8;

    f32x4 acc[4][2];
#pragma unroll
    for (int mt = 0; mt < 4; ++mt)
#pragma unroll
        for (int nt = 0; nt < 2; ++nt) acc[mt][nt] = (f32x4){0.f, 0.f, 0.f, 0.f};

#define STAGE(buf, k0) do { \
        GL16(Ag0 + (k0), &As[buf][w * 512]); \
        GL16(Ag1 + (k0), &As[buf][2048 + w * 512]); \
        GL16(Wg0 + (k0), &Bs[buf][w * 512]); \
    } while (0)

    const int swl = (lr >> 1) & 3;
#define COMPUTE(buf) do { \
        bf16x8 af[4], bf[2]; \
        _Pragma("unroll") \
        for (int mt = 0; mt < 4; ++mt) \
            af[mt] = *(const bf16x8*)&As[buf][(wm * 64 + mt * 16 + lr) * 32 + (lg ^ swl) * 8]; \
        _Pragma("unroll") \
        for (int nt = 0; nt < 2; ++nt) \
            bf[nt] = *(const bf16x8*)&Bs[buf][(wn * 32 + nt * 16 + lr) * 32 + (lg ^ swl) * 8]; \
        _Pragma("unroll") \
        for (int mt = 0; mt < 4; ++mt) \
            _Pragma("unroll") \
            for (int nt = 0; nt < 2; ++nt) \
                acc[mt][nt] = __builtin_amdgcn_mfma_f32_16x16x32_bf16(af[mt], bf[nt], acc[mt][nt], 0, 0, 0); \
    } while (0)

    STAGE(0, 0);
    __syncthreads();
    const int nk = K / 32;
    for (int t = 0; t < nk - 1; ++t) {
        STAGE((t + 1) & 1, (size_t)(t + 1) * 32);
        COMPUTE(t & 1);
        __syncthreads();
    }
    COMPUTE((nk - 1) & 1);

    float bv[2];
#pragma unroll
    for (int nt = 0; nt < 2; ++nt) bv[nt] = bias[n0 + wn * 32 + nt * 16 + lr];
#pragma unroll
    for (int mt = 0; mt < 4; ++mt)
#pragma unroll
        for (int r4 = 0; r4 < 4; ++r4) {
            size_t m = m0 + wm * 64 + mt * 16 + lg * 4 + r4;
            float* crow = Cf + m * N + n0 + wn * 32 + lr;
#pragma unroll
            for (int nt = 0; nt < 2; ++nt)
                crow[nt * 16] = acc[mt][nt][r4] + bv[nt];
        }
#undef STAGE
#undef COMPUTE
}

// ---------------------------------------------------------------------------
// prep_kernel: qtab (MFMA) + V-transpose + tvT2 + fm->u8 (unchanged)
// ---------------------------------------------------------------------------
__global__ __launch_bounds__(256) void prep_kernel(const ushort* __restrict__ qb,
                                                   const float* __restrict__ table_k,
                                                   const ushort* __restrict__ vb,
                                                   const float* __restrict__ table_v,
                                                   const int* __restrict__ fmat,
                                                   ushort* __restrict__ qtab,
                                                   ushort* __restrict__ vT,
                                                   ushort* __restrict__ tvT2,
                                                   uchar* __restrict__ fm8) {
    __shared__ __align__(16) ushort shmem[144 * 72];
    const int wg  = blockIdx.x;
    const int tid = threadIdx.x;

    if (wg < 256) {
        const int h    = wg & 15;
        const int half = (wg >> 4) & 1;
        const int b    = wg >> 5;
        const int q0   = half * 256;
        ushort* tk = shmem;
        for (int i = tid; i < TAB * 8; i += 256) {
            int row = i >> 3, gr = i & 7;
            const float* src = table_k + row * HD + gr * 8;
            float4 a = *(const float4*)src;
            float4 c = *(const float4*)(src + 4);
            uint4 u;
            u.x = pk(a.x, a.y); u.y = pk(a.z, a.w);
            u.z = pk(c.x, c.y); u.w = pk(c.z, c.w);
            *(uint4*)&tk[row * 72 + gr * 8] = u;
        }
        __syncthreads();

        const int w  = tid >> 6;
        const int l  = tid & 63;
        const int lr = l & 15;
        const int lg = l >> 4;
        bf16x8 qf[4][2];
#pragma unroll
        for (int qt = 0; qt < 4; ++qt) {
            const ushort* qrow = qb + ((size_t)(b * SEQ) + q0 + w * 64 + qt * 16 + lr) * HID + h * HD;
            qf[qt][0] = *(const bf16x8*)(qrow + lg * 8);
            qf[qt][1] = *(const bf16x8*)(qrow + 32 + lg * 8);
        }
        ushort* outbase = qtab + ((size_t)(b * HEADS + h) * SEQ + q0 + w * 64) * QSTR;
#pragma unroll
        for (int mt = 0; mt < 9; ++mt) {
            bf16x8 tf0 = *(const bf16x8*)&tk[(mt * 16 + lr) * 72 + lg * 8];
            bf16x8 tf1 = *(const bf16x8*)&tk[(mt * 16 + lr) * 72 + 32 + lg * 8];
#pragma unroll
            for (int qt = 0; qt < 4; ++qt) {
                f32x4 acc = (f32x4){0.f, 0.f, 0.f, 0.f};
                acc = __builtin_amdgcn_mfma_f32_16x16x32_bf16(tf0, qf[qt][0], acc, 0, 0, 0);
                acc = __builtin_amdgcn_mfma_f32_16x16x32_bf16(tf1, qf[qt][1], acc, 0, 0, 0);
                ushort* orow = outbase + (size_t)(qt * 16 + lr) * QSTR;
                if (mt < 8) {
                    uint2 pu;
                    pu.x = pk(acc[0], acc[1]); pu.y = pk(acc[2], acc[3]);
                    *(uint2*)&orow[mt * 16 + lg * 4] = pu;
                } else if (lg == 0) {
                    orow[128] = f2b(acc[0]);
                }
            }
        }
    } else if (wg < 768) {
        const int vw = wg - 256;
        ushort* tile = shmem;
        const int b = vw >> 6, h = (vw >> 2) & 15, kc = vw & 3;
        const int k0 = kc * 128;
        {
            const int kr = tid >> 1, dc = (tid & 1) * 32;
            const ushort* src = vb + ((size_t)(b * SEQ) + k0 + kr) * HID + h * 64 + dc;
#pragma unroll
            for (int j = 0; j < 4; ++j) {
                uint4 u = *(const uint4*)(src + j * 8);
                *(uint4*)&tile[kr * 72 + dc + j * 8] = u;
            }
        }
        __syncthreads();
        {
            const int dr = tid >> 2, kc2 = (tid & 3) * 32;
            ushort* dst = vT + ((size_t)(b * 16 + h) * 64 + dr) * 512 + k0 + kc2;
#pragma unroll
            for (int j = 0; j < 4; ++j) {
                U16x8 o;
#pragma unroll
                for (int i = 0; i < 8; ++i)
                    o.s[i] = tile[(kc2 + j * 8 + i) * 72 + dr];
                *(uint4*)(dst + j * 8) = o.q;
            }
        }
    } else if (wg == 768) {
        for (int i = tid; i < 64 * 160; i += 256) {
            int d = i / 160;
            int c = i - d * 160;
            tvT2[i] = (c < TAB) ? f2b(table_v[(size_t)c * HD + d]) : (ushort)0;
        }
    } else {
        const size_t base = (size_t)(wg - 769) * 2048 + (size_t)tid * 8;
        int4 a = *(const int4*)(fmat + base);
        int4 c = *(const int4*)(fmat + base + 4);
        uint lo = (uint)a.x | ((uint)a.y << 8) | ((uint)a.z << 16) | ((uint)a.w << 24);
        uint hi = (uint)c.x | ((uint)c.y << 8) | ((uint)c.z << 16) | ((uint)c.w << 24);
        uint2 o; o.x = lo; o.y = hi;
        *(uint2*)(fm8 + base) = o;
    }
}

// ---------------------------------------------------------------------------
// qk_gemm: S[bh, q, k] = Q . K^T  (bf16 out, unchanged)
// ---------------------------------------------------------------------------
__global__ __launch_bounds__(256) void qk_gemm(const ushort* __restrict__ qb,
                                               const ushort* __restrict__ kb,
                                               ushort* __restrict__ S) {
    __shared__ ushort As[2][128 * 32];
    __shared__ ushort Bs[2][128 * 32];
    const int tid = threadIdx.x;
    const int m0 = blockIdx.x * 128;
    const int n0 = blockIdx.y * 128;
    const int bh = blockIdx.z;
    const int b = bh >> 4, h = bh & 15;
    const size_t rowQ = (size_t)b * SEQ;

    const int w  = tid >> 6;
    const int l  = tid & 63;
    const int lr = l & 15;
    const int lg = l >> 4;
    const int wm = w >> 1;
    const int wn = w & 1;

    const int sr = tid >> 2;
    const int sc = tid & 3;
    const int g  = sc ^ ((sr >> 1) & 3);
    const ushort* Ag0 = qb + (rowQ + m0 + sr)      * HID + h * HD + g * 8;
    const ushort* Ag1 = qb + (rowQ + m0 + sr + 64) * HID + h * HD + g * 8;
    const ushort* Wg0 = kb + (rowQ + n0 + sr)      * HID + h * HD + g * 8;
    const ushort* Wg1 = kb + (rowQ + n0 + sr + 64) * HID + h * HD + g * 8;

    GL16(Ag0,      &As[0][w * 512]); GL16(Ag1,      &As[0][2048 + w * 512]);
    GL16(Wg0,      &Bs[0][w * 512]); GL16(Wg1,      &Bs[0][2048 + w * 512]);
    GL16(Ag0 + 32, &As[1][w * 512]); GL16(Ag1 + 32, &As[1][2048 + w * 512]);
    GL16(Wg0 + 32, &Bs[1][w * 512]); GL16(Wg1 + 32, &Bs[1][2048 + w * 512]);

    f32x4 acc[4][4];
#pragma unroll
    for (int mt = 0; mt < 4; ++mt)
#pragma unroll
        for (int nt = 0; nt < 4; ++nt) acc[mt][nt] = (f32x4){0.f, 0.f, 0.f, 0.f};

    const int swl = (lr >> 1) & 3;
    __syncthreads();
#pragma unroll
    for (int buf = 0; buf < 2; ++buf) {
        bf16x8 af[4], bf[4];
#pragma unroll
        for (int mt = 0; mt < 4; ++mt)
            af[mt] = *(const bf16x8*)&As[buf][(wm * 64 + mt * 16 + lr) * 32 + (lg ^ swl) * 8];
#pragma unroll
        for (int nt = 0; nt < 4; ++nt)
            bf[nt] = *(const bf16x8*)&Bs[buf][(wn * 64 + nt * 16 + lr) * 32 + (lg ^ swl) * 8];
#pragma unroll
        for (int mt = 0; mt < 4; ++mt)
#pragma unroll
            for (int nt = 0; nt < 4; ++nt)
                acc[mt][nt] = __builtin_amdgcn_mfma_f32_16x16x32_bf16(af[mt], bf[nt], acc[mt][nt], 0, 0, 0);
    }

    ushort* Sb = S + (size_t)bh * SEQ * SEQ;
#pragma unroll
    for (int mt = 0; mt < 4; ++mt)
#pragma unroll
        for (int r4 = 0; r4 < 4; ++r4) {
            int m = m0 + wm * 64 + mt * 16 + lg * 4 + r4;
            ushort* srow = Sb + (size_t)m * SEQ + n0 + wn * 64 + lr;
#pragma unroll
            for (int nt = 0; nt < 4; ++nt)
                srow[nt * 16] = f2b(acc[mt][nt][r4]);
        }
}

// ---------------------------------------------------------------------------
// smpv v2 (k-split): 512 thr / 8 waves; wave = (rowgroup rg=w&3, k-half kh=w>>2).
// Each wave: 8 k-iterations over its 256-k half (chain halved), bins shared
// u32 ds_add, w2 t-chunks split by kh, O partials reduced via obuf (overlays
// dead qtb). 3 barriers. ~52KB LDS -> 3 blocks/CU = 24 waves/CU.
// ---------------------------------------------------------------------------
__global__ __launch_bounds__(512, 4) void smpv_kernel(const ushort* __restrict__ S,
                                                      const uchar* __restrict__ fm8,
                                                      const ushort* __restrict__ qt,
                                                      const ushort* __restrict__ vT,
                                                      const ushort* __restrict__ tvT2,
                                                      ushort* __restrict__ x) {
    constexpr float FIX = 65536.0f;
    constexpr float INV_FIX = 1.0f / 65536.0f;
    __shared__ __align__(16) uint   bins[64 * 132];    // 33,792 B
    __shared__ __align__(16) ushort qtb[64 * QSTR];    // 17,408 B (obuf overlay)
    __shared__ float rowsum[2][64];

    const int tid = threadIdx.x;
    const int w   = tid >> 6;         // 0..7
    const int l   = tid & 63;
    const int lr  = l & 15;
    const int lg  = l >> 4;
    const int rg  = w & 3;            // row group: rows rg*16..rg*16+15
    const int kh  = w >> 2;           // k-half: [kh*256, kh*256+256)

    // XCD swizzle: 1024 blocks, 128/XCD
    const int bid = blockIdx.x;
    const int swz = (bid & 7) * 128 + (bid >> 3);
    const int bh  = swz >> 3;
    const int m0  = (swz & 7) * 64;
    const int b   = bh >> 4, h = bh & 15;

    // ---- prologue: stage qtab rows, zero bins ----
    {
        const uint4* src = (const uint4*)(qt + ((size_t)bh * SEQ + m0) * QSTR);
        uint4* dst = (uint4*)qtb;
        for (int i = tid; i < 64 * QSTR / 8; i += 512) dst[i] = src[i];
    }
    {
        uint4 z = {0u, 0u, 0u, 0u};
        uint4* dz = (uint4*)bins;
        for (int i = tid; i < 64 * 132 / 4; i += 512) dz[i] = z;
    }
    LDS_BARRIER();                                     // barrier 1

    const int myrow = rg * 16 + lr;
    const int kbase = kh * 256;
    const ushort* Srow  = S + ((size_t)bh * SEQ + m0 + myrow) * SEQ + kbase;
    const uchar*  fmrow = fm8 + ((size_t)(b * SEQ) + m0 + myrow) * SEQ + kbase;
    const ushort* qrow  = qtb + myrow * QSTR;
    uint*         brow  = bins + myrow * 132;
    const ushort* vbase = vT + (size_t)bh * 64 * 512 + kbase;

    f32x4 acc[4];
#pragma unroll
    for (int nt = 0; nt < 4; ++nt) acc[nt] = (f32x4){0.f, 0.f, 0.f, 0.f};
    float lsum = 0.f;

    for (int ks = 0; ks < 8; ++ks) {
        const int k0 = ks * 32 + lg * 8;
        U16x8 sv;
        sv.q = *(const uint4*)(Srow + k0);
        uint2 fm = *(const uint2*)(fmrow + k0);
        int ts[8];
        ts[0] = fm.x & 255; ts[1] = (fm.x >> 8) & 255;
        ts[2] = (fm.x >> 16) & 255; ts[3] = fm.x >> 24;
        ts[4] = fm.y & 255; ts[5] = (fm.y >> 8) & 255;
        ts[6] = (fm.y >> 16) & 255; ts[7] = fm.y >> 24;
        float p[8];
#pragma unroll
        for (int j = 0; j < 8; ++j) {
            p[j] = __expf((b2f(sv.s[j]) + b2f(qrow[ts[j]])) * 0.125f);
            lsum += p[j];
        }
#pragma unroll
        for (int j = 0; j < 8; ++j)
            __hip_atomic_fetch_add(&brow[ts[j]], (uint)(p[j] * FIX),
                                   __ATOMIC_RELAXED, __HIP_MEMORY_SCOPE_WORKGROUP);
        bf16x8 af = pack8(p[0], p[1], p[2], p[3], p[4], p[5], p[6], p[7]);
#pragma unroll
        for (int nt = 0; nt < 4; ++nt) {
            bf16x8 bf_ = *(const bf16x8*)(vbase + (size_t)(nt * 16 + lr) * 512 + k0);
            acc[nt] = __builtin_amdgcn_mfma_f32_16x16x32_bf16(af, bf_, acc[nt], 0, 0, 0);
        }
    }
    lsum += __shfl_xor(lsum, 16);
    lsum += __shfl_xor(lsum, 32);
    if (lg == 0) rowsum[kh][myrow] = lsum;

    LDS_BARRIER();                                     // barrier 2: bins done, qtb dead

    // ---- w2: wave does t-chunks [kh*2, kh*2+2) of 4 (each 32 t) ----
#pragma unroll
    for (int c = 0; c < 2; ++c) {
        const int t0 = (kh * 2 + c) * 32 + lg * 8;
        const uint* bp = brow + t0;
        bf16x8 af = pack8((float)bp[0] * INV_FIX, (float)bp[1] * INV_FIX,
                          (float)bp[2] * INV_FIX, (float)bp[3] * INV_FIX,
                          (float)bp[4] * INV_FIX, (float)bp[5] * INV_FIX,
                          (float)bp[6] * INV_FIX, (float)bp[7] * INV_FIX);
#pragma unroll
        for (int nt = 0; nt < 4; ++nt) {
            bf16x8 bf_ = *(const bf16x8*)(tvT2 + (size_t)(nt * 16 + lr) * 160 + t0);
            acc[nt] = __builtin_amdgcn_mfma_f32_16x16x32_bf16(af, bf_, acc[nt], 0, 0, 0);
        }
    }

    // ---- kh=1 waves write partials into obuf (overlays qtb) ----
    float* obuf = (float*)qtb;                         // 16 KB used of 17 KB
    if (kh == 1) {
#pragma unroll
        for (int nt = 0; nt < 4; ++nt)
            *(f32x4*)&obuf[((rg * 4 + nt) * 64 + l) * 4] = acc[nt];
    }
    LDS_BARRIER();                                     // barrier 3

    if (kh == 0) {
#pragma unroll
        for (int nt = 0; nt < 4; ++nt) {
            f32x4 p_ = *(const f32x4*)&obuf[((rg * 4 + nt) * 64 + l) * 4];
            acc[nt][0] += p_[0]; acc[nt][1] += p_[1];
            acc[nt][2] += p_[2]; acc[nt][3] += p_[3];
        }
        float iv[4], nb[4];
#pragma unroll
        for (int r = 0; r < 4; ++r) {
            const int crow = rg * 16 + lg * 4 + r;
            iv[r] = 1.f / (rowsum[0][crow] + rowsum[1][crow]);
            nb[r] = (float)bins[crow * 132 + 128] * INV_FIX;
        }
#pragma unroll
        for (int nt = 0; nt < 4; ++nt) {
            float tv = b2f(tvT2[(size_t)(nt * 16 + lr) * 160 + 128]);
#pragma unroll
            for (int r = 0; r < 4; ++r)
                acc[nt][r] = (acc[nt][r] + nb[r] * tv) * iv[r];
        }
        ushort* orow = x + ((size_t)(b * SEQ) + m0 + rg * 16 + lg * 4) * HID + h * HD;
#pragma unroll
        for (int r = 0; r < 4; ++r)
#pragma unroll
            for (int nt = 0; nt < 4; ++nt)
                orow[(size_t)r * HID + nt * 16 + lr] = f2b(acc[nt][r]);
    }
}

// ---------------------------------------------------------------------------
extern "C" void kernel_launch(void* const* d_in, const int* in_sizes, int n_in,
                              void* d_out, int out_size, void* d_ws, size_t ws_size,
                              hipStream_t stream) {
    const float* query = (const float*)d_in[0];
    const float* key   = (const float*)d_in[1];
    const float* value = (const float*)d_in[2];
    const int*   fmat  = (const int*)d_in[3];
    const float* Wq = (const float*)d_in[4];
    const float* bq = (const float*)d_in[5];
    const float* Wk = (const float*)d_in[6];
    const float* bk = (const float*)d_in[7];
    const float* Wv = (const float*)d_in[8];
    const float* bv = (const float*)d_in[9];
    const float* Wo = (const float*)d_in[10];
    const float* bo = (const float*)d_in[11];
    const float* table_k = (const float*)d_in[12];
    const float* table_v = (const float*)d_in[13];

    const size_t nBLD = (size_t)BATCH * SEQ * HID;
    const size_t nW   = (size_t)HID * HID;
    ushort* us = (ushort*)d_ws;
    ushort* qin16 = us;                 us += nBLD;   // reused as vT
    ushort* kin16 = us;                 us += nBLD;   // reused as tvT2
    ushort* vin16 = us;                 us += nBLD;
    ushort* wq16  = us;                 us += nW;
    ushort* wk16  = us;                 us += nW;
    ushort* wv16  = us;                 us += nW;
    ushort* wo16  = us;                 us += nW;
    ushort* qb16  = us;                 us += nBLD;
    ushort* kb16  = us;                 us += nBLD;
    ushort* vb16  = us;                 us += nBLD;
    ushort* qt16  = us;                 us += (size_t)BATCH * HEADS * SEQ * QSTR;
    ushort* xb16  = us;                 us += nBLD;
    uchar*  fm8   = (uchar*)us;         us += (size_t)BATCH * SEQ * SEQ / 2;
    ushort* Sbuf  = us;                 us += (size_t)BATCH * HEADS * SEQ * SEQ;

    ConvArgs ca;
    ca.src[0] = query; ca.src[1] = key; ca.src[2] = value;
    ca.src[3] = Wq; ca.src[4] = Wk; ca.src[5] = Wv; ca.src[6] = Wo;
    ca.dst[0] = qin16; ca.dst[1] = kin16; ca.dst[2] = vin16;
    ca.dst[3] = wq16; ca.dst[4] = wk16; ca.dst[5] = wv16; ca.dst[6] = wo16;
    convert_bf16<<<dim3(8192), 256, 0, stream>>>(ca);

    GemmArgs gq = {};
    gq.A[0] = qin16; gq.A[1] = kin16; gq.A[2] = vin16;
    gq.W[0] = wq16;  gq.W[1] = wk16;  gq.W[2] = wv16;
    gq.bias[0] = bq; gq.bias[1] = bk; gq.bias[2] = bv;
    gq.Cb[0] = qb16; gq.Cb[1] = kb16; gq.Cb[2] = vb16;
    gemm_qkv<<<dim3(768), 256, 0, stream>>>(gq);

    ushort* vTbuf  = qin16;
    ushort* tvTbuf = kin16;

    prep_kernel<<<dim3(1793), 256, 0, stream>>>(qb16, table_k, vb16, table_v,
                                                fmat, qt16, vTbuf, tvTbuf, fm8);

    qk_gemm<<<dim3(4, 4, 128), 256, 0, stream>>>(qb16, kb16, Sbuf);
    smpv_kernel<<<dim3(1024), 512, 0, stream>>>(Sbuf, fm8, qt16, vTbuf, tvTbuf, xb16);

    gemm_wo<<<dim3(512), 256, 0, stream>>>(xb16, wo16, bo, (float*)d_out);
}

// Round 17
// 167.277 us; speedup vs baseline: 1.0723x; 1.0024x over previous
//
#include <hip/hip_runtime.h>

#define HID 1024
#define HEADS 16
#define HD 64
#define TAB 129
#define QSTR 136
#define BATCH 8
#define SEQ 512

typedef unsigned int uint;
typedef unsigned short ushort;
typedef unsigned char uchar;
typedef __attribute__((ext_vector_type(4))) float f32x4;
typedef __attribute__((ext_vector_type(8))) __bf16 bf16x8;

__device__ __forceinline__ ushort f2b(float x) {
    uint b = __float_as_uint(x);
    uint r = (b + 0x7fffu + ((b >> 16) & 1u)) >> 16;
    return (ushort)r;
}
__device__ __forceinline__ uint pk(float lo, float hi) {
    return (uint)f2b(lo) | ((uint)f2b(hi) << 16);
}
__device__ __forceinline__ float b2f(ushort u) {
    return __uint_as_float(((uint)u) << 16);
}
union U16x8 { uint u[4]; bf16x8 v; ushort s[8]; uint4 q; };
__device__ __forceinline__ bf16x8 pack8(float a0, float a1, float a2, float a3,
                                        float a4, float a5, float a6, float a7) {
    U16x8 r;
    r.u[0] = pk(a0, a1); r.u[1] = pk(a2, a3);
    r.u[2] = pk(a4, a5); r.u[3] = pk(a6, a7);
    return r.v;
}

#define GL16(gp, lp) __builtin_amdgcn_global_load_lds( \
    (const __attribute__((address_space(1))) void*)(gp), \
    (__attribute__((address_space(3))) void*)(lp), 16, 0, 0)

#define LDS_BARRIER() do { \
        asm volatile("s_waitcnt lgkmcnt(0)" ::: "memory"); \
        __builtin_amdgcn_s_barrier(); \
    } while (0)

// ---------------------------------------------------------------------------
// convert fp32 -> bf16 (unchanged)
// ---------------------------------------------------------------------------
struct ConvArgs { const float* src[7]; ushort* dst[7]; };

__global__ __launch_bounds__(256) void convert_bf16(ConvArgs ca) {
    int bid = blockIdx.x;
    int ti, lb;
    if (bid < 6144) { ti = bid >> 11; lb = bid & 2047; }
    else { int r = bid - 6144; ti = 3 + (r >> 9); lb = r & 511; }
    const float* s = ca.src[ti] + (size_t)lb * 2048 + (threadIdx.x << 3);
    ushort*      d = ca.dst[ti] + (size_t)lb * 2048 + (threadIdx.x << 3);
    float4 a = *(const float4*)s;
    float4 c = *(const float4*)(s + 4);
    uint4 u;
    u.x = pk(a.x, a.y); u.y = pk(a.z, a.w);
    u.z = pk(c.x, c.y); u.w = pk(c.z, c.w);
    *(uint4*)d = u;
}

// ---------------------------------------------------------------------------
// QKV GEMM: 128x128 tile, z-batched, flattened XCD-bijective grid (768 blk).
// ---------------------------------------------------------------------------
struct GemmArgs {
    const ushort* A[3];
    const ushort* W[3];
    const float*  bias[3];
    ushort*       Cb[3];
};

__global__ __launch_bounds__(256) void gemm_qkv(GemmArgs ga) {
    const int N = HID, K = HID;
    __shared__ ushort As[2][128 * 32];
    __shared__ ushort Bs[2][128 * 32];
    const int tid = threadIdx.x;
    const int bid = blockIdx.x;
    const int swz = (bid & 7) * 96 + (bid >> 3);   // 768 blocks, 96/XCD
    const int z   = swz >> 8;
    const int rem = swz & 255;
    const int m0  = (rem >> 3) * 128;
    const int n0  = (rem & 7) * 128;
    const ushort* A = ga.A[z];
    const ushort* W = ga.W[z];

    const int w  = tid >> 6;
    const int l  = tid & 63;
    const int lr = l & 15;
    const int lg = l >> 4;
    const int wm = w >> 1;
    const int wn = w & 1;

    const int sr = tid >> 2;
    const int sc = tid & 3;
    const int g  = sc ^ ((sr >> 1) & 3);
    const ushort* Ag0 = A + (size_t)(m0 + sr)      * K + g * 8;
    const ushort* Ag1 = A + (size_t)(m0 + sr + 64) * K + g * 8;
    const ushort* Wg0 = W + (size_t)(n0 + sr)      * K + g * 8;
    const ushort* Wg1 = W + (size_t)(n0 + sr + 64) * K + g * 8;

    f32x4 acc[4][4];
#pragma unroll
    for (int mt = 0; mt < 4; ++mt)
#pragma unroll
        for (int nt = 0; nt < 4; ++nt) acc[mt][nt] = (f32x4){0.f, 0.f, 0.f, 0.f};

#define STAGE(buf, k0) do { \
        GL16(Ag0 + (k0), &As[buf][w * 512]); \
        GL16(Ag1 + (k0), &As[buf][2048 + w * 512]); \
        GL16(Wg0 + (k0), &Bs[buf][w * 512]); \
        GL16(Wg1 + (k0), &Bs[buf][2048 + w * 512]); \
    } while (0)

    const int swl = (lr >> 1) & 3;
#define COMPUTE(buf) do { \
        bf16x8 af[4], bf[4]; \
        _Pragma("unroll") \
        for (int mt = 0; mt < 4; ++mt) \
            af[mt] = *(const bf16x8*)&As[buf][(wm * 64 + mt * 16 + lr) * 32 + (lg ^ swl) * 8]; \
        _Pragma("unroll") \
        for (int nt = 0; nt < 4; ++nt) \
            bf[nt] = *(const bf16x8*)&Bs[buf][(wn * 64 + nt * 16 + lr) * 32 + (lg ^ swl) * 8]; \
        _Pragma("unroll") \
        for (int mt = 0; mt < 4; ++mt) \
            _Pragma("unroll") \
            for (int nt = 0; nt < 4; ++nt) \
                acc[mt][nt] = __builtin_amdgcn_mfma_f32_16x16x32_bf16(af[mt], bf[nt], acc[mt][nt], 0, 0, 0); \
    } while (0)

    STAGE(0, 0);
    __syncthreads();
    const int nk = K / 32;
    for (int t = 0; t < nk - 1; ++t) {
        STAGE((t + 1) & 1, (size_t)(t + 1) * 32);
        COMPUTE(t & 1);
        __syncthreads();
    }
    COMPUTE((nk - 1) & 1);

    const float* bias = ga.bias[z];
    float bv[4];
#pragma unroll
    for (int nt = 0; nt < 4; ++nt) bv[nt] = bias[n0 + wn * 64 + nt * 16 + lr];
    ushort* Cb = ga.Cb[z];
#pragma unroll
    for (int mt = 0; mt < 4; ++mt)
#pragma unroll
        for (int r4 = 0; r4 < 4; ++r4) {
            size_t m = m0 + wm * 64 + mt * 16 + lg * 4 + r4;
            ushort* crow = Cb + m * N + n0 + wn * 64 + lr;
#pragma unroll
            for (int nt = 0; nt < 4; ++nt)
                crow[nt * 16] = f2b(acc[mt][nt][r4] + bv[nt]);
        }
#undef STAGE
#undef COMPUTE
}

// ---------------------------------------------------------------------------
// Wo GEMM, BN=64 tile, flattened XCD-bijective grid (512 blk, unchanged)
// ---------------------------------------------------------------------------
__global__ __launch_bounds__(256) void gemm_wo(const ushort* __restrict__ A,
                                               const ushort* __restrict__ W,
                                               const float* __restrict__ bias,
                                               float* __restrict__ Cf) {
    const int N = HID, K = HID;
    __shared__ ushort As[2][128 * 32];
    __shared__ ushort Bs[2][64 * 32];
    const int tid = threadIdx.x;
    const int bid = blockIdx.x;
    const int swz = (bid & 7) * 64 + (bid >> 3);
    const int m0 = (swz >> 4) * 128;
    const int n0 = (swz & 15) * 64;

    const int w  = tid >> 6;
    const int l  = tid & 63;
    const int lr = l & 15;
    const int lg = l >> 4;
    const int wm = w >> 1;
    const int wn = w & 1;

    const int sr = tid >> 2;
    const int sc = tid & 3;
    const int g  = sc ^ ((sr >> 1) & 3);
    const ushort* Ag0 = A + (size_t)(m0 + sr)      * K + g * 8;
    const ushort* Ag1 = A + (size_t)(m0 + sr + 64) * K + g * 8;
    const ushort* Wg0 = W + (size_t)(n0 + sr)      * K + g * 8;

    f32x4 acc[4][2];
#pragma unroll
    for (int mt = 0; mt < 4; ++mt)
#pragma unroll
        for (int nt = 0; nt < 2; ++nt) acc[mt][nt] = (f32x4){0.f, 0.f, 0.f, 0.f};

#define STAGE(buf, k0) do { \
        GL16(Ag0 + (k0), &As[buf][w * 512]); \
        GL16(Ag1 + (k0), &As[buf][2048 + w * 512]); \
        GL16(Wg0 + (k0), &Bs[buf][w * 512]); \
    } while (0)

    const int swl = (lr >> 1) & 3;
#define COMPUTE(buf) do { \
        bf16x8 af[4], bf[2]; \
        _Pragma("unroll") \
        for (int mt = 0; mt < 4; ++mt) \
            af[mt] = *(const bf16x8*)&As[buf][(wm * 64 + mt * 16 + lr) * 32 + (lg ^ swl) * 8]; \
        _Pragma("unroll") \
        for (int nt = 0; nt < 2; ++nt) \
            bf[nt] = *(const bf16x8*)&Bs[buf][(wn * 32 + nt * 16 + lr) * 32 + (lg ^ swl) * 8]; \
        _Pragma("unroll") \
        for (int mt = 0; mt < 4; ++mt) \
            _Pragma("unroll") \
            for (int nt = 0; nt < 2; ++nt) \
                acc[mt][nt] = __builtin_amdgcn_mfma_f32_16x16x32_bf16(af[mt], bf[nt], acc[mt][nt], 0, 0, 0); \
    } while (0)

    STAGE(0, 0);
    __syncthreads();
    const int nk = K / 32;
    for (int t = 0; t < nk - 1; ++t) {
        STAGE((t + 1) & 1, (size_t)(t + 1) * 32);
        COMPUTE(t & 1);
        __syncthreads();
    }
    COMPUTE((nk - 1) & 1);

    float bv[2];
#pragma unroll
    for (int nt = 0; nt < 2; ++nt) bv[nt] = bias[n0 + wn * 32 + nt * 16 + lr];
#pragma unroll
    for (int mt = 0; mt < 4; ++mt)
#pragma unroll
        for (int r4 = 0; r4 < 4; ++r4) {
            size_t m = m0 + wm * 64 + mt * 16 + lg * 4 + r4;
            float* crow = Cf + m * N + n0 + wn * 32 + lr;
#pragma unroll
            for (int nt = 0; nt < 2; ++nt)
                crow[nt * 16] = acc[mt][nt][r4] + bv[nt];
        }
#undef STAGE
#undef COMPUTE
}

// ---------------------------------------------------------------------------
// prep_kernel: qtab (MFMA) + V-transpose + tvT2 + fm->u8 (unchanged)
// ---------------------------------------------------------------------------
__global__ __launch_bounds__(256) void prep_kernel(const ushort* __restrict__ qb,
                                                   const float* __restrict__ table_k,
                                                   const ushort* __restrict__ vb,
                                                   const float* __restrict__ table_v,
                                                   const int* __restrict__ fmat,
                                                   ushort* __restrict__ qtab,
                                                   ushort* __restrict__ vT,
                                                   ushort* __restrict__ tvT2,
                                                   uchar* __restrict__ fm8) {
    __shared__ __align__(16) ushort shmem[144 * 72];
    const int wg  = blockIdx.x;
    const int tid = threadIdx.x;

    if (wg < 256) {
        const int h    = wg & 15;
        const int half = (wg >> 4) & 1;
        const int b    = wg >> 5;
        const int q0   = half * 256;
        ushort* tk = shmem;
        for (int i = tid; i < TAB * 8; i += 256) {
            int row = i >> 3, gr = i & 7;
            const float* src = table_k + row * HD + gr * 8;
            float4 a = *(const float4*)src;
            float4 c = *(const float4*)(src + 4);
            uint4 u;
            u.x = pk(a.x, a.y); u.y = pk(a.z, a.w);
            u.z = pk(c.x, c.y); u.w = pk(c.z, c.w);
            *(uint4*)&tk[row * 72 + gr * 8] = u;
        }
        __syncthreads();

        const int w  = tid >> 6;
        const int l  = tid & 63;
        const int lr = l & 15;
        const int lg = l >> 4;
        bf16x8 qf[4][2];
#pragma unroll
        for (int qt = 0; qt < 4; ++qt) {
            const ushort* qrow = qb + ((size_t)(b * SEQ) + q0 + w * 64 + qt * 16 + lr) * HID + h * HD;
            qf[qt][0] = *(const bf16x8*)(qrow + lg * 8);
            qf[qt][1] = *(const bf16x8*)(qrow + 32 + lg * 8);
        }
        ushort* outbase = qtab + ((size_t)(b * HEADS + h) * SEQ + q0 + w * 64) * QSTR;
#pragma unroll
        for (int mt = 0; mt < 9; ++mt) {
            bf16x8 tf0 = *(const bf16x8*)&tk[(mt * 16 + lr) * 72 + lg * 8];
            bf16x8 tf1 = *(const bf16x8*)&tk[(mt * 16 + lr) * 72 + 32 + lg * 8];
#pragma unroll
            for (int qt = 0; qt < 4; ++qt) {
                f32x4 acc = (f32x4){0.f, 0.f, 0.f, 0.f};
                acc = __builtin_amdgcn_mfma_f32_16x16x32_bf16(tf0, qf[qt][0], acc, 0, 0, 0);
                acc = __builtin_amdgcn_mfma_f32_16x16x32_bf16(tf1, qf[qt][1], acc, 0, 0, 0);
                ushort* orow = outbase + (size_t)(qt * 16 + lr) * QSTR;
                if (mt < 8) {
                    uint2 pu;
                    pu.x = pk(acc[0], acc[1]); pu.y = pk(acc[2], acc[3]);
                    *(uint2*)&orow[mt * 16 + lg * 4] = pu;
                } else if (lg == 0) {
                    orow[128] = f2b(acc[0]);
                }
            }
        }
    } else if (wg < 768) {
        const int vw = wg - 256;
        ushort* tile = shmem;
        const int b = vw >> 6, h = (vw >> 2) & 15, kc = vw & 3;
        const int k0 = kc * 128;
        {
            const int kr = tid >> 1, dc = (tid & 1) * 32;
            const ushort* src = vb + ((size_t)(b * SEQ) + k0 + kr) * HID + h * 64 + dc;
#pragma unroll
            for (int j = 0; j < 4; ++j) {
                uint4 u = *(const uint4*)(src + j * 8);
                *(uint4*)&tile[kr * 72 + dc + j * 8] = u;
            }
        }
        __syncthreads();
        {
            const int dr = tid >> 2, kc2 = (tid & 3) * 32;
            ushort* dst = vT + ((size_t)(b * 16 + h) * 64 + dr) * 512 + k0 + kc2;
#pragma unroll
            for (int j = 0; j < 4; ++j) {
                U16x8 o;
#pragma unroll
                for (int i = 0; i < 8; ++i)
                    o.s[i] = tile[(kc2 + j * 8 + i) * 72 + dr];
                *(uint4*)(dst + j * 8) = o.q;
            }
        }
    } else if (wg == 768) {
        for (int i = tid; i < 64 * 160; i += 256) {
            int d = i / 160;
            int c = i - d * 160;
            tvT2[i] = (c < TAB) ? f2b(table_v[(size_t)c * HD + d]) : (ushort)0;
        }
    } else {
        const size_t base = (size_t)(wg - 769) * 2048 + (size_t)tid * 8;
        int4 a = *(const int4*)(fmat + base);
        int4 c = *(const int4*)(fmat + base + 4);
        uint lo = (uint)a.x | ((uint)a.y << 8) | ((uint)a.z << 16) | ((uint)a.w << 24);
        uint hi = (uint)c.x | ((uint)c.y << 8) | ((uint)c.z << 16) | ((uint)c.w << 24);
        uint2 o; o.x = lo; o.y = hi;
        *(uint2*)(fm8 + base) = o;
    }
}

// ---------------------------------------------------------------------------
// qk_gemm: S[bh, q, k] = Q . K^T  (bf16 out, unchanged)
// ---------------------------------------------------------------------------
__global__ __launch_bounds__(256) void qk_gemm(const ushort* __restrict__ qb,
                                               const ushort* __restrict__ kb,
                                               ushort* __restrict__ S) {
    __shared__ ushort As[2][128 * 32];
    __shared__ ushort Bs[2][128 * 32];
    const int tid = threadIdx.x;
    const int m0 = blockIdx.x * 128;
    const int n0 = blockIdx.y * 128;
    const int bh = blockIdx.z;
    const int b = bh >> 4, h = bh & 15;
    const size_t rowQ = (size_t)b * SEQ;

    const int w  = tid >> 6;
    const int l  = tid & 63;
    const int lr = l & 15;
    const int lg = l >> 4;
    const int wm = w >> 1;
    const int wn = w & 1;

    const int sr = tid >> 2;
    const int sc = tid & 3;
    const int g  = sc ^ ((sr >> 1) & 3);
    const ushort* Ag0 = qb + (rowQ + m0 + sr)      * HID + h * HD + g * 8;
    const ushort* Ag1 = qb + (rowQ + m0 + sr + 64) * HID + h * HD + g * 8;
    const ushort* Wg0 = kb + (rowQ + n0 + sr)      * HID + h * HD + g * 8;
    const ushort* Wg1 = kb + (rowQ + n0 + sr + 64) * HID + h * HD + g * 8;

    GL16(Ag0,      &As[0][w * 512]); GL16(Ag1,      &As[0][2048 + w * 512]);
    GL16(Wg0,      &Bs[0][w * 512]); GL16(Wg1,      &Bs[0][2048 + w * 512]);
    GL16(Ag0 + 32, &As[1][w * 512]); GL16(Ag1 + 32, &As[1][2048 + w * 512]);
    GL16(Wg0 + 32, &Bs[1][w * 512]); GL16(Wg1 + 32, &Bs[1][2048 + w * 512]);

    f32x4 acc[4][4];
#pragma unroll
    for (int mt = 0; mt < 4; ++mt)
#pragma unroll
        for (int nt = 0; nt < 4; ++nt) acc[mt][nt] = (f32x4){0.f, 0.f, 0.f, 0.f};

    const int swl = (lr >> 1) & 3;
    __syncthreads();
#pragma unroll
    for (int buf = 0; buf < 2; ++buf) {
        bf16x8 af[4], bf[4];
#pragma unroll
        for (int mt = 0; mt < 4; ++mt)
            af[mt] = *(const bf16x8*)&As[buf][(wm * 64 + mt * 16 + lr) * 32 + (lg ^ swl) * 8];
#pragma unroll
        for (int nt = 0; nt < 4; ++nt)
            bf[nt] = *(const bf16x8*)&Bs[buf][(wn * 64 + nt * 16 + lr) * 32 + (lg ^ swl) * 8];
#pragma unroll
        for (int mt = 0; mt < 4; ++mt)
#pragma unroll
            for (int nt = 0; nt < 4; ++nt)
                acc[mt][nt] = __builtin_amdgcn_mfma_f32_16x16x32_bf16(af[mt], bf[nt], acc[mt][nt], 0, 0, 0);
    }

    ushort* Sb = S + (size_t)bh * SEQ * SEQ;
#pragma unroll
    for (int mt = 0; mt < 4; ++mt)
#pragma unroll
        for (int r4 = 0; r4 < 4; ++r4) {
            int m = m0 + wm * 64 + mt * 16 + lg * 4 + r4;
            ushort* srow = Sb + (size_t)m * SEQ + n0 + wn * 64 + lr;
#pragma unroll
            for (int nt = 0; nt < 4; ++nt)
                srow[nt * 16] = f2b(acc[mt][nt][r4]);
        }
}

// ---------------------------------------------------------------------------
// smpv v3: k-split (8 waves = 4 rowgroups x 2 k-halves) + batched S/fm
// register loads with a hard sched_barrier(0) so the 16 VMEM ops issue in one
// window (R12's per-value fences failed; this cannot be crossed). Phase 2:
// 64 independent LDS gathers + exp + bins -> paf[] fragments; phase 3: pure
// {V-load + MFMA} stream. 3 barriers, ~52KB LDS.
// ---------------------------------------------------------------------------
__global__ __launch_bounds__(512, 4) void smpv_kernel(const ushort* __restrict__ S,
                                                      const uchar* __restrict__ fm8,
                                                      const ushort* __restrict__ qt,
                                                      const ushort* __restrict__ vT,
                                                      const ushort* __restrict__ tvT2,
                                                      ushort* __restrict__ x) {
    constexpr float FIX = 65536.0f;
    constexpr float INV_FIX = 1.0f / 65536.0f;
    __shared__ __align__(16) uint   bins[64 * 132];    // 33,792 B
    __shared__ __align__(16) ushort qtb[64 * QSTR];    // 17,408 B (obuf overlay)
    __shared__ float rowsum[2][64];

    const int tid = threadIdx.x;
    const int w   = tid >> 6;
    const int l   = tid & 63;
    const int lr  = l & 15;
    const int lg  = l >> 4;
    const int rg  = w & 3;
    const int kh  = w >> 2;

    const int bid = blockIdx.x;
    const int swz = (bid & 7) * 128 + (bid >> 3);
    const int bh  = swz >> 3;
    const int m0  = (swz & 7) * 64;
    const int b   = bh >> 4, h = bh & 15;

    // ---- prologue: stage qtab rows, zero bins ----
    {
        const uint4* src = (const uint4*)(qt + ((size_t)bh * SEQ + m0) * QSTR);
        uint4* dst = (uint4*)qtb;
        for (int i = tid; i < 64 * QSTR / 8; i += 512) dst[i] = src[i];
    }
    {
        uint4 z = {0u, 0u, 0u, 0u};
        uint4* dz = (uint4*)bins;
        for (int i = tid; i < 64 * 132 / 4; i += 512) dz[i] = z;
    }
    LDS_BARRIER();                                     // barrier 1

    const int myrow = rg * 16 + lr;
    const int kbase = kh * 256;
    const ushort* Srow  = S + ((size_t)bh * SEQ + m0 + myrow) * SEQ + kbase;
    const uchar*  fmrow = fm8 + ((size_t)(b * SEQ) + m0 + myrow) * SEQ + kbase;
    const ushort* qrow  = qtb + myrow * QSTR;
    uint*         brow  = bins + myrow * 132;
    const ushort* vbase = vT + (size_t)bh * 64 * 512 + kbase;

    // ---- phase 1: batched S + fm loads (16 VMEM ops, one latency window) ----
    U16x8 sv[8];
    uint2 fmv[8];
#pragma unroll
    for (int i = 0; i < 8; ++i) {
        const int k0 = i * 32 + lg * 8;
        sv[i].q = *(const uint4*)(Srow + k0);
        fmv[i]  = *(const uint2*)(fmrow + k0);
    }
    __builtin_amdgcn_sched_barrier(0);   // hard fence: loads cannot sink past

    // ---- phase 2: gathers + exp + bins + fragment pack (all independent) ----
    f32x4 acc[4];
#pragma unroll
    for (int nt = 0; nt < 4; ++nt) acc[nt] = (f32x4){0.f, 0.f, 0.f, 0.f};
    float lsum = 0.f;
    bf16x8 paf[8];
#pragma unroll
    for (int i = 0; i < 8; ++i) {
        const uint2 fm = fmv[i];
        int ts[8];
        ts[0] = fm.x & 255; ts[1] = (fm.x >> 8) & 255;
        ts[2] = (fm.x >> 16) & 255; ts[3] = fm.x >> 24;
        ts[4] = fm.y & 255; ts[5] = (fm.y >> 8) & 255;
        ts[6] = (fm.y >> 16) & 255; ts[7] = fm.y >> 24;
        float p[8];
#pragma unroll
        for (int j = 0; j < 8; ++j) {
            p[j] = __expf((b2f(sv[i].s[j]) + b2f(qrow[ts[j]])) * 0.125f);
            lsum += p[j];
        }
#pragma unroll
        for (int j = 0; j < 8; ++j)
            __hip_atomic_fetch_add(&brow[ts[j]], (uint)(p[j] * FIX),
                                   __ATOMIC_RELAXED, __HIP_MEMORY_SCOPE_WORKGROUP);
        paf[i] = pack8(p[0], p[1], p[2], p[3], p[4], p[5], p[6], p[7]);
    }
    lsum += __shfl_xor(lsum, 16);
    lsum += __shfl_xor(lsum, 32);
    if (lg == 0) rowsum[kh][myrow] = lsum;

    // ---- phase 3: pure {V-load + MFMA} stream ----
#pragma unroll
    for (int i = 0; i < 8; ++i) {
        const int k0 = i * 32 + lg * 8;
#pragma unroll
        for (int nt = 0; nt < 4; ++nt) {
            bf16x8 bf_ = *(const bf16x8*)(vbase + (size_t)(nt * 16 + lr) * 512 + k0);
            acc[nt] = __builtin_amdgcn_mfma_f32_16x16x32_bf16(paf[i], bf_, acc[nt], 0, 0, 0);
        }
    }

    LDS_BARRIER();                                     // barrier 2: bins done, qtb dead

    // ---- w2: wave does t-chunks [kh*2, kh*2+2) of 4 (each 32 t) ----
#pragma unroll
    for (int c = 0; c < 2; ++c) {
        const int t0 = (kh * 2 + c) * 32 + lg * 8;
        const uint* bp = brow + t0;
        bf16x8 af = pack8((float)bp[0] * INV_FIX, (float)bp[1] * INV_FIX,
                          (float)bp[2] * INV_FIX, (float)bp[3] * INV_FIX,
                          (float)bp[4] * INV_FIX, (float)bp[5] * INV_FIX,
                          (float)bp[6] * INV_FIX, (float)bp[7] * INV_FIX);
#pragma unroll
        for (int nt = 0; nt < 4; ++nt) {
            bf16x8 bf_ = *(const bf16x8*)(tvT2 + (size_t)(nt * 16 + lr) * 160 + t0);
            acc[nt] = __builtin_amdgcn_mfma_f32_16x16x32_bf16(af, bf_, acc[nt], 0, 0, 0);
        }
    }

    // ---- kh=1 waves write partials into obuf (overlays qtb) ----
    float* obuf = (float*)qtb;
    if (kh == 1) {
#pragma unroll
        for (int nt = 0; nt < 4; ++nt)
            *(f32x4*)&obuf[((rg * 4 + nt) * 64 + l) * 4] = acc[nt];
    }
    LDS_BARRIER();                                     // barrier 3

    if (kh == 0) {
#pragma unroll
        for (int nt = 0; nt < 4; ++nt) {
            f32x4 p_ = *(const f32x4*)&obuf[((rg * 4 + nt) * 64 + l) * 4];
            acc[nt][0] += p_[0]; acc[nt][1] += p_[1];
            acc[nt][2] += p_[2]; acc[nt][3] += p_[3];
        }
        float iv[4], nb[4];
#pragma unroll
        for (int r = 0; r < 4; ++r) {
            const int crow = rg * 16 + lg * 4 + r;
            iv[r] = 1.f / (rowsum[0][crow] + rowsum[1][crow]);
            nb[r] = (float)bins[crow * 132 + 128] * INV_FIX;
        }
#pragma unroll
        for (int nt = 0; nt < 4; ++nt) {
            float tv = b2f(tvT2[(size_t)(nt * 16 + lr) * 160 + 128]);
#pragma unroll
            for (int r = 0; r < 4; ++r)
                acc[nt][r] = (acc[nt][r] + nb[r] * tv) * iv[r];
        }
        ushort* orow = x + ((size_t)(b * SEQ) + m0 + rg * 16 + lg * 4) * HID + h * HD;
#pragma unroll
        for (int r = 0; r < 4; ++r)
#pragma unroll
            for (int nt = 0; nt < 4; ++nt)
                orow[(size_t)r * HID + nt * 16 + lr] = f2b(acc[nt][r]);
    }
}

// ---------------------------------------------------------------------------
extern "C" void kernel_launch(void* const* d_in, const int* in_sizes, int n_in,
                              void* d_out, int out_size, void* d_ws, size_t ws_size,
                              hipStream_t stream) {
    const float* query = (const float*)d_in[0];
    const float* key   = (const float*)d_in[1];
    const float* value = (const float*)d_in[2];
    const int*   fmat  = (const int*)d_in[3];
    const float* Wq = (const float*)d_in[4];
    const float* bq = (const float*)d_in[5];
    const float* Wk = (const float*)d_in[6];
    const float* bk = (const float*)d_in[7];
    const float* Wv = (const float*)d_in[8];
    const float* bv = (const float*)d_in[9];
    const float* Wo = (const float*)d_in[10];
    const float* bo = (const float*)d_in[11];
    const float* table_k = (const float*)d_in[12];
    const float* table_v = (const float*)d_in[13];

    const size_t nBLD = (size_t)BATCH * SEQ * HID;
    const size_t nW   = (size_t)HID * HID;
    ushort* us = (ushort*)d_ws;
    ushort* qin16 = us;                 us += nBLD;   // reused as vT
    ushort* kin16 = us;                 us += nBLD;   // reused as tvT2
    ushort* vin16 = us;                 us += nBLD;
    ushort* wq16  = us;                 us += nW;
    ushort* wk16  = us;                 us += nW;
    ushort* wv16  = us;                 us += nW;
    ushort* wo16  = us;                 us += nW;
    ushort* qb16  = us;                 us += nBLD;
    ushort* kb16  = us;                 us += nBLD;
    ushort* vb16  = us;                 us += nBLD;
    ushort* qt16  = us;                 us += (size_t)BATCH * HEADS * SEQ * QSTR;
    ushort* xb16  = us;                 us += nBLD;
    uchar*  fm8   = (uchar*)us;         us += (size_t)BATCH * SEQ * SEQ / 2;
    ushort* Sbuf  = us;                 us += (size_t)BATCH * HEADS * SEQ * SEQ;

    ConvArgs ca;
    ca.src[0] = query; ca.src[1] = key; ca.src[2] = value;
    ca.src[3] = Wq; ca.src[4] = Wk; ca.src[5] = Wv; ca.src[6] = Wo;
    ca.dst[0] = qin16; ca.dst[1] = kin16; ca.dst[2] = vin16;
    ca.dst[3] = wq16; ca.dst[4] = wk16; ca.dst[5] = wv16; ca.dst[6] = wo16;
    convert_bf16<<<dim3(8192), 256, 0, stream>>>(ca);

    GemmArgs gq = {};
    gq.A[0] = qin16; gq.A[1] = kin16; gq.A[2] = vin16;
    gq.W[0] = wq16;  gq.W[1] = wk16;  gq.W[2] = wv16;
    gq.bias[0] = bq; gq.bias[1] = bk; gq.bias[2] = bv;
    gq.Cb[0] = qb16; gq.Cb[1] = kb16; gq.Cb[2] = vb16;
    gemm_qkv<<<dim3(768), 256, 0, stream>>>(gq);

    ushort* vTbuf  = qin16;
    ushort* tvTbuf = kin16;

    prep_kernel<<<dim3(1793), 256, 0, stream>>>(qb16, table_k, vb16, table_v,
                                                fmat, qt16, vTbuf, tvTbuf, fm8);

    qk_gemm<<<dim3(4, 4, 128), 256, 0, stream>>>(qb16, kb16, Sbuf);
    smpv_kernel<<<dim3(1024), 512, 0, stream>>>(Sbuf, fm8, qt16, vTbuf, tvTbuf, xb16);

    gemm_wo<<<dim3(512), 256, 0, stream>>>(xb16, wo16, bo, (float*)d_out);
}